// Round 1
// baseline (1021.348 us; speedup 1.0000x reference)
//
#include <hip/hip_runtime.h>
#include <hip/hip_bf16.h>
#include <stdint.h>

typedef __bf16 bf16x8 __attribute__((ext_vector_type(8)));
typedef float f32x4 __attribute__((ext_vector_type(4)));
typedef unsigned short u16x8 __attribute__((ext_vector_type(8)));

#define B_ROWS 8192
#define K_DIM  2048
#define O_DIM  256
#define N_BINS 64
#define J_DIM  (O_DIM * N_BINS)   // 16384

#define BM 128
#define BN 128
#define BK 32

__device__ __forceinline__ unsigned short f2bf(float f) {
    union { float f; unsigned u; } v; v.f = f;
    unsigned r = (v.u + 0x7fffu + ((v.u >> 16) & 1u)) >> 16;
    return (unsigned short)r;
}

// ---- conversion kernels ------------------------------------------------
__global__ void cvt_x_kernel(const float* __restrict__ x, unsigned short* __restrict__ xb) {
    int i = (blockIdx.x * 256 + threadIdx.x) * 4;
    float4 v = *(const float4*)(x + i);
    ushort4 o;
    o.x = f2bf(v.x); o.y = f2bf(v.y); o.z = f2bf(v.z); o.w = f2bf(v.w);
    *(ushort4*)(xb + i) = o;
}

// Vb[p][i] = bf16(W[p&255][p>>8][i])  (row permutation fused into the pack)
__global__ void cvt_w_kernel(const float* __restrict__ W, unsigned short* __restrict__ vb) {
    int bid = blockIdx.x;
    int p   = bid >> 1;
    int i0  = (bid & 1) * 1024 + threadIdx.x * 4;
    int src = (p & (O_DIM - 1)) * (N_BINS * K_DIM) + (p >> 8) * K_DIM + i0;
    float4 v = *(const float4*)(W + src);
    ushort4 o;
    o.x = f2bf(v.x); o.y = f2bf(v.y); o.z = f2bf(v.z); o.w = f2bf(v.w);
    *(ushort4*)(vb + (size_t)p * K_DIM + i0) = o;
}

__device__ __forceinline__ u16x8 pack8(float4 a, float4 b) {
    u16x8 r;
    r[0] = f2bf(a.x); r[1] = f2bf(a.y); r[2] = f2bf(a.z); r[3] = f2bf(a.w);
    r[4] = f2bf(b.x); r[5] = f2bf(b.y); r[6] = f2bf(b.z); r[7] = f2bf(b.w);
    return r;
}

// ---- GEMM: logits[b][j] = sum_k x[b][k] * V[j][k] + bias[j] ------------
// PRE=true : xb/vb pre-packed bf16, global_load_lds staging (fast path)
// PRE=false: convert f32->bf16 in registers while staging (ws too small)
template <bool PRE>
__global__ __launch_bounds__(256) void gemm_kernel(
    const unsigned short* __restrict__ xb,
    const unsigned short* __restrict__ vb,
    const float* __restrict__ xf,
    const float* __restrict__ Wf,
    const float* __restrict__ bias,
    float* __restrict__ logits)
{
    __shared__ unsigned short Asm_[BM * BK];
    __shared__ unsigned short Bsm_[BN * BK];

    const int tid = threadIdx.x;
    const int bid = blockIdx.x;
    // XCD-aware swizzle: 8192 blocks, 8 XCDs, 1024 blocks/XCD (bijective)
    const int swz = (bid & 7) * 1024 + (bid >> 3);
    const int bm = swz >> 7;       // 64 row tiles
    const int bn = swz & 127;      // 128 col tiles
    const int row0 = bm * BM;
    const int col0 = bn * BN;

    const int lane = tid & 63;
    const int wid  = tid >> 6;
    const int wr   = wid >> 1;
    const int wc   = wid & 1;

    f32x4 acc[4][4];
#pragma unroll
    for (int m = 0; m < 4; ++m)
#pragma unroll
        for (int n = 0; n < 4; ++n)
            acc[m][n] = (f32x4){0.f, 0.f, 0.f, 0.f};

    // staging: chunk c = s*256+tid (s=0,1): row=c>>2 (0..127), 16B piece c&3
    const int srow  = tid >> 2;
    const int koff  = (tid & 3) * 8;       // element offset within the 32-wide K tile

    const int ra0 = row0 + srow, ra1 = row0 + 64 + srow;
    const int rb0 = col0 + srow, rb1 = col0 + 64 + srow;

    unsigned short* la0 = &Asm_[tid * 8];
    unsigned short* la1 = &Asm_[(256 + tid) * 8];
    unsigned short* lb0 = &Bsm_[tid * 8];
    unsigned short* lb1 = &Bsm_[(256 + tid) * 8];

    // fast-path global srcs (bf16, element units)
    const unsigned short* ga0 = PRE ? xb + (size_t)ra0 * K_DIM + koff : nullptr;
    const unsigned short* ga1 = PRE ? xb + (size_t)ra1 * K_DIM + koff : nullptr;
    const unsigned short* gb0 = PRE ? vb + (size_t)rb0 * K_DIM + koff : nullptr;
    const unsigned short* gb1 = PRE ? vb + (size_t)rb1 * K_DIM + koff : nullptr;

    // slow-path f32 srcs (W rows permuted on the fly)
    const float* fa0 = nullptr; const float* fa1 = nullptr;
    const float* fb0 = nullptr; const float* fb1 = nullptr;
    if (!PRE) {
        fa0 = xf + (size_t)ra0 * K_DIM + koff;
        fa1 = xf + (size_t)ra1 * K_DIM + koff;
        fb0 = Wf + (size_t)((rb0 & (O_DIM - 1)) * (N_BINS * K_DIM) + (rb0 >> 8) * K_DIM) + koff;
        fb1 = Wf + (size_t)((rb1 & (O_DIM - 1)) * (N_BINS * K_DIM) + (rb1 >> 8) * K_DIM) + koff;
    }

    // LDS fragment read offsets (ushort indices; 16B aligned)
    const int a_row  = wr * 64 + (lane & 15);
    const int b_row  = wc * 64 + (lane & 15);
    const int k_half = (lane >> 4) * 8;

    for (int kt = 0; kt < K_DIM / BK; ++kt) {
        const int kbase = kt * BK;
        if (PRE) {
            __builtin_amdgcn_global_load_lds((const __attribute__((address_space(1))) void*)(ga0 + kbase),
                                             (__attribute__((address_space(3))) void*)la0, 16, 0, 0);
            __builtin_amdgcn_global_load_lds((const __attribute__((address_space(1))) void*)(ga1 + kbase),
                                             (__attribute__((address_space(3))) void*)la1, 16, 0, 0);
            __builtin_amdgcn_global_load_lds((const __attribute__((address_space(1))) void*)(gb0 + kbase),
                                             (__attribute__((address_space(3))) void*)lb0, 16, 0, 0);
            __builtin_amdgcn_global_load_lds((const __attribute__((address_space(1))) void*)(gb1 + kbase),
                                             (__attribute__((address_space(3))) void*)lb1, 16, 0, 0);
        } else {
            *(u16x8*)la0 = pack8(*(const float4*)(fa0 + kbase), *(const float4*)(fa0 + kbase + 4));
            *(u16x8*)la1 = pack8(*(const float4*)(fa1 + kbase), *(const float4*)(fa1 + kbase + 4));
            *(u16x8*)lb0 = pack8(*(const float4*)(fb0 + kbase), *(const float4*)(fb0 + kbase + 4));
            *(u16x8*)lb1 = pack8(*(const float4*)(fb1 + kbase), *(const float4*)(fb1 + kbase + 4));
        }
        __syncthreads();   // drains vmcnt/lgkmcnt -> LDS tile ready

        bf16x8 af[4], bg[4];
#pragma unroll
        for (int m = 0; m < 4; ++m)
            af[m] = *(const bf16x8*)&Asm_[(a_row + m * 16) * BK + k_half];
#pragma unroll
        for (int n = 0; n < 4; ++n)
            bg[n] = *(const bf16x8*)&Bsm_[(b_row + n * 16) * BK + k_half];

#pragma unroll
        for (int m = 0; m < 4; ++m)
#pragma unroll
            for (int n = 0; n < 4; ++n)
                acc[m][n] = __builtin_amdgcn_mfma_f32_16x16x32_bf16(af[m], bg[n], acc[m][n], 0, 0, 0);

        __syncthreads();   // all waves done reading before next stage overwrites
    }

    // epilogue: C/D layout col = lane&15, row = (lane>>4)*4 + reg   [m89]
    const int r_base = row0 + wr * 64 + (lane >> 4) * 4;
    const int c_base = col0 + wc * 64 + (lane & 15);
#pragma unroll
    for (int n = 0; n < 4; ++n) {
        const int c = c_base + n * 16;
        const float bv = bias[(c & (O_DIM - 1)) * N_BINS + (c >> 8)];
#pragma unroll
        for (int m = 0; m < 4; ++m) {
            const int r = r_base + m * 16;
            float* out = logits + (size_t)r * J_DIM + c;
#pragma unroll
            for (int q = 0; q < 4; ++q)
                out[(size_t)q * J_DIM] = acc[m][n][q] + bv;
        }
    }
}

// ---- gumbel-softmax + grid dot ----------------------------------------
// one 16-lane group per (b, o) row of 64 bins; float4 per lane
__global__ void softmax_encode_kernel(
    const float* __restrict__ logits,
    const float* __restrict__ gumbel,
    const float* __restrict__ grid,
    float* __restrict__ encoded)
{
    int t = blockIdx.x * 256 + threadIdx.x;
    int g = t >> 4;
    int l = t & 15;
    size_t base = (size_t)g * 64 + l * 4;
    float4 L = *(const float4*)(logits + base);
    float4 G = *(const float4*)(gumbel + base);
    float4 gr = *(const float4*)(grid + l * 4);

    float z0 = (L.x + G.x) * 2.0f;   // / TAU, TAU=0.5
    float z1 = (L.y + G.y) * 2.0f;
    float z2 = (L.z + G.z) * 2.0f;
    float z3 = (L.w + G.w) * 2.0f;

    float m = fmaxf(fmaxf(z0, z1), fmaxf(z2, z3));
#pragma unroll
    for (int s = 1; s < 16; s <<= 1) m = fmaxf(m, __shfl_xor(m, s, 16));

    float e0 = __expf(z0 - m), e1 = __expf(z1 - m), e2 = __expf(z2 - m), e3 = __expf(z3 - m);
    float ssum = e0 + e1 + e2 + e3;
    float dsum = e0 * gr.x + e1 * gr.y + e2 * gr.z + e3 * gr.w;
#pragma unroll
    for (int s = 1; s < 16; s <<= 1) {
        ssum += __shfl_xor(ssum, s, 16);
        dsum += __shfl_xor(dsum, s, 16);
    }
    if (l == 0) encoded[g] = dsum / ssum;
}

// ---- launch -------------------------------------------------------------
extern "C" void kernel_launch(void* const* d_in, const int* in_sizes, int n_in,
                              void* d_out, int out_size, void* d_ws, size_t ws_size,
                              hipStream_t stream) {
    const float* x      = (const float*)d_in[0];
    const float* W      = (const float*)d_in[1];
    const float* bias   = (const float*)d_in[2];
    const float* grid   = (const float*)d_in[3];
    const float* gumbel = (const float*)d_in[4];

    float* encoded = (float*)d_out;                                   // [8192][256]
    float* logits  = (float*)d_out + (size_t)B_ROWS * O_DIM;          // [8192][16384]

    const size_t xb_bytes = (size_t)B_ROWS * K_DIM * 2;   // 32 MiB
    const size_t vb_bytes = (size_t)J_DIM * K_DIM * 2;    // 64 MiB
    const int n_gemm_blocks = (B_ROWS / BM) * (J_DIM / BN);           // 8192

    if (ws_size >= xb_bytes + vb_bytes) {
        unsigned short* xb = (unsigned short*)d_ws;
        unsigned short* vb = (unsigned short*)((char*)d_ws + xb_bytes);
        cvt_x_kernel<<<(B_ROWS * K_DIM) / 1024, 256, 0, stream>>>(x, xb);
        cvt_w_kernel<<<J_DIM * 2, 256, 0, stream>>>(W, vb);
        gemm_kernel<true><<<n_gemm_blocks, 256, 0, stream>>>(xb, vb, nullptr, nullptr, bias, logits);
    } else {
        gemm_kernel<false><<<n_gemm_blocks, 256, 0, stream>>>(nullptr, nullptr, x, W, bias, logits);
    }

    softmax_encode_kernel<<<(B_ROWS * O_DIM * 16) / 256, 256, 0, stream>>>(logits, gumbel, grid, encoded);
}

// Round 2
// 865.336 us; speedup vs baseline: 1.1803x; 1.1803x over previous
//
#include <hip/hip_runtime.h>
#include <hip/hip_bf16.h>
#include <stdint.h>

typedef __bf16 bf16x8 __attribute__((ext_vector_type(8)));
typedef float f32x4 __attribute__((ext_vector_type(4)));
typedef unsigned short u16x8 __attribute__((ext_vector_type(8)));

#define B_ROWS 8192
#define K_DIM  2048
#define O_DIM  256
#define N_BINS 64
#define J_DIM  (O_DIM * N_BINS)   // 16384
#define NT     (K_DIM / 64)       // 32 K-tiles of BK=64

__device__ __forceinline__ unsigned short f2bf(float f) {
    union { float f; unsigned u; } v; v.f = f;
    unsigned r = (v.u + 0x7fffu + ((v.u >> 16) & 1u)) >> 16;
    return (unsigned short)r;
}

// ---- conversion kernels ------------------------------------------------
__global__ void cvt_x_kernel(const float* __restrict__ x, unsigned short* __restrict__ xb) {
    int i = (blockIdx.x * 256 + threadIdx.x) * 4;
    float4 v = *(const float4*)(x + i);
    ushort4 o;
    o.x = f2bf(v.x); o.y = f2bf(v.y); o.z = f2bf(v.z); o.w = f2bf(v.w);
    *(ushort4*)(xb + i) = o;
}

// Vb[p][i] = bf16(W[p&255][p>>8][i])  (row permutation fused into the pack)
__global__ void cvt_w_kernel(const float* __restrict__ W, unsigned short* __restrict__ vb) {
    int bid = blockIdx.x;
    int p   = bid >> 1;
    int i0  = (bid & 1) * 1024 + threadIdx.x * 4;
    int src = (p & (O_DIM - 1)) * (N_BINS * K_DIM) + (p >> 8) * K_DIM + i0;
    float4 v = *(const float4*)(W + src);
    ushort4 o;
    o.x = f2bf(v.x); o.y = f2bf(v.y); o.z = f2bf(v.z); o.w = f2bf(v.w);
    *(ushort4*)(vb + (size_t)p * K_DIM + i0) = o;
}

__device__ __forceinline__ u16x8 pack8(float4 a, float4 b) {
    u16x8 r;
    r[0] = f2bf(a.x); r[1] = f2bf(a.y); r[2] = f2bf(a.z); r[3] = f2bf(a.w);
    r[4] = f2bf(b.x); r[5] = f2bf(b.y); r[6] = f2bf(b.z); r[7] = f2bf(b.w);
    return r;
}

// ---- 256x256 8-phase GEMM ---------------------------------------------
#define GLDS(gsrc, ldst) \
    __builtin_amdgcn_global_load_lds((const __attribute__((address_space(1))) void*)(gsrc), \
                                     (__attribute__((address_space(3))) void*)(ldst), 16, 0, 0)
#define SBAR()   __builtin_amdgcn_s_barrier()
#define SCHED0() __builtin_amdgcn_sched_barrier(0)
#define WAIT_VM(N)   do { asm volatile("s_waitcnt vmcnt(" #N ")" ::: "memory"); } while (0)
#define WAIT_LGKM0() do { asm volatile("s_waitcnt lgkmcnt(0)" ::: "memory"); SCHED0(); } while (0)
#define MFMA(a, b, c) (c) = __builtin_amdgcn_mfma_f32_16x16x32_bf16((a), (b), (c), 0, 0, 0)

__global__ __launch_bounds__(512, 2) void gemm8_kernel(
    const unsigned short* __restrict__ xb,
    const unsigned short* __restrict__ vb,
    const float* __restrict__ bias,
    float* __restrict__ logits)
{
    // [buf][kk-half][row][32 K-elems]; each [256][32] quarter = 16 KB, contiguous
    __shared__ unsigned short As[2][2][256][32];
    __shared__ unsigned short Bs[2][2][256][32];

    const int tid  = threadIdx.x;
    const int lane = tid & 63;
    const int wv   = tid >> 6;
    const int wr   = wv >> 2;      // 0..1  -> A rows wr*128..+127
    const int wc   = wv & 3;       // 0..3  -> B cols wc*64..+63

    const int bid = blockIdx.x;
    // XCD swizzle (2048 blocks, 2048%8==0 -> bijective), then 4(bm)x64(bn) chunk per XCD
    const int swz  = (bid & 7) * 256 + (bid >> 3);
    const int bm   = (swz >> 8) * 4 + (swz & 3);   // 0..31
    const int bn   = (swz & 255) >> 2;             // 0..63
    const int row0 = bm * 256;
    const int col0 = bn * 256;

    // staging source coords with inverse-swizzle (involution: byte ^= ((byte>>9)&1)<<5)
    const int oss = (tid * 16) ^ (tid & 32);   // byte offset within 8 KB chunk, pre-swizzled
    const int sr  = oss >> 6;                  // row 0..127 within chunk
    const int sc  = (oss >> 1) & 31;           // K-elem 0..31 (multiple of 8)

    const unsigned short* gA = xb + (size_t)(row0 + sr) * K_DIM + sc;
    const unsigned short* gB = vb + (size_t)(col0 + sr) * K_DIM + sc;

    auto stageA = [&](int kt, int h, int b) {
        const unsigned short* g = gA + kt * 64 + h * 32;
        unsigned short* l = &As[b][h][0][0] + wv * 512;
        GLDS(g, l);
        GLDS(g + (size_t)128 * K_DIM, l + 4096);
    };
    auto stageB = [&](int kt, int h, int b) {
        const unsigned short* g = gB + kt * 64 + h * 32;
        unsigned short* l = &Bs[b][h][0][0] + wv * 512;
        GLDS(g, l);
        GLDS(g + (size_t)128 * K_DIM, l + 4096);
    };

    // fragment read coords; swizzled slot (element ^16 when lane&8, matching stage involution)
    const int arb  = wr * 128 + (lane & 15);
    const int brb  = wc * 64 + (lane & 15);
    const int slot = ((lane >> 4) * 8) ^ ((lane & 8) << 1);

    f32x4 acc[8][4];
#pragma unroll
    for (int m = 0; m < 8; ++m)
#pragma unroll
        for (int n = 0; n < 4; ++n)
            acc[m][n] = (f32x4){0.f, 0.f, 0.f, 0.f};

    bf16x8 af[8], b0, b1;

    // prologue: stage K-tile 0 fully; K0 quarters resident, K1 quarters in flight
    stageA(0, 0, 0); stageB(0, 0, 0); stageA(0, 1, 0); stageB(0, 1, 0);
    WAIT_VM(4); SCHED0(); SBAR(); SCHED0();

    for (int kt = 0; kt < NT - 1; ++kt) {
        const int cur = kt & 1, nxt = cur ^ 1;
        // ---- ph0: kk0, n0-1 ----
#pragma unroll
        for (int m = 0; m < 8; ++m) af[m] = *(const bf16x8*)&As[cur][0][arb + m * 16][slot];
        b0 = *(const bf16x8*)&Bs[cur][0][brb][slot];
        b1 = *(const bf16x8*)&Bs[cur][0][brb + 16][slot];
        stageA(kt + 1, 0, nxt);
        SBAR(); WAIT_LGKM0();
        __builtin_amdgcn_s_setprio(1);
#pragma unroll
        for (int m = 0; m < 8; ++m) { MFMA(af[m], b0, acc[m][0]); MFMA(af[m], b1, acc[m][1]); }
        __builtin_amdgcn_s_setprio(0);
        SBAR();
        // ---- ph1: kk0, n2-3 ----
        b0 = *(const bf16x8*)&Bs[cur][0][brb + 32][slot];
        b1 = *(const bf16x8*)&Bs[cur][0][brb + 48][slot];
        stageB(kt + 1, 0, nxt);
        WAIT_VM(4); SCHED0(); SBAR(); SCHED0();   // kt's K1 quarters now resident
        WAIT_LGKM0();
        __builtin_amdgcn_s_setprio(1);
#pragma unroll
        for (int m = 0; m < 8; ++m) { MFMA(af[m], b0, acc[m][2]); MFMA(af[m], b1, acc[m][3]); }
        __builtin_amdgcn_s_setprio(0);
        SBAR();
        // ---- ph2: kk1, n2-3 ----
#pragma unroll
        for (int m = 0; m < 8; ++m) af[m] = *(const bf16x8*)&As[cur][1][arb + m * 16][slot];
        b0 = *(const bf16x8*)&Bs[cur][1][brb + 32][slot];
        b1 = *(const bf16x8*)&Bs[cur][1][brb + 48][slot];
        stageA(kt + 1, 1, nxt);
        SBAR(); WAIT_LGKM0();
        __builtin_amdgcn_s_setprio(1);
#pragma unroll
        for (int m = 0; m < 8; ++m) { MFMA(af[m], b0, acc[m][2]); MFMA(af[m], b1, acc[m][3]); }
        __builtin_amdgcn_s_setprio(0);
        SBAR();
        // ---- ph3: kk1, n0-1 ----
        b0 = *(const bf16x8*)&Bs[cur][1][brb][slot];
        b1 = *(const bf16x8*)&Bs[cur][1][brb + 16][slot];
        stageB(kt + 1, 1, nxt);
        WAIT_VM(4); SCHED0(); SBAR(); SCHED0();   // kt+1's K0 quarters now resident
        WAIT_LGKM0();
        __builtin_amdgcn_s_setprio(1);
#pragma unroll
        for (int m = 0; m < 8; ++m) { MFMA(af[m], b0, acc[m][0]); MFMA(af[m], b1, acc[m][1]); }
        __builtin_amdgcn_s_setprio(0);
        SBAR();
    }

    // ---- last K-tile (no staging) ----
    {
        const int cur = (NT - 1) & 1;
#pragma unroll
        for (int m = 0; m < 8; ++m) af[m] = *(const bf16x8*)&As[cur][0][arb + m * 16][slot];
        b0 = *(const bf16x8*)&Bs[cur][0][brb][slot];
        b1 = *(const bf16x8*)&Bs[cur][0][brb + 16][slot];
        SBAR(); WAIT_LGKM0();
        __builtin_amdgcn_s_setprio(1);
#pragma unroll
        for (int m = 0; m < 8; ++m) { MFMA(af[m], b0, acc[m][0]); MFMA(af[m], b1, acc[m][1]); }
        __builtin_amdgcn_s_setprio(0);
        SBAR();
        b0 = *(const bf16x8*)&Bs[cur][0][brb + 32][slot];
        b1 = *(const bf16x8*)&Bs[cur][0][brb + 48][slot];
        WAIT_VM(0); SCHED0(); SBAR(); SCHED0();   // last K1 quarters resident
        WAIT_LGKM0();
        __builtin_amdgcn_s_setprio(1);
#pragma unroll
        for (int m = 0; m < 8; ++m) { MFMA(af[m], b0, acc[m][2]); MFMA(af[m], b1, acc[m][3]); }
        __builtin_amdgcn_s_setprio(0);
        SBAR();
#pragma unroll
        for (int m = 0; m < 8; ++m) af[m] = *(const bf16x8*)&As[cur][1][arb + m * 16][slot];
        b0 = *(const bf16x8*)&Bs[cur][1][brb + 32][slot];
        b1 = *(const bf16x8*)&Bs[cur][1][brb + 48][slot];
        SBAR(); WAIT_LGKM0();
        __builtin_amdgcn_s_setprio(1);
#pragma unroll
        for (int m = 0; m < 8; ++m) { MFMA(af[m], b0, acc[m][2]); MFMA(af[m], b1, acc[m][3]); }
        __builtin_amdgcn_s_setprio(0);
        SBAR();
        b0 = *(const bf16x8*)&Bs[cur][1][brb][slot];
        b1 = *(const bf16x8*)&Bs[cur][1][brb + 16][slot];
        WAIT_LGKM0();
        __builtin_amdgcn_s_setprio(1);
#pragma unroll
        for (int m = 0; m < 8; ++m) { MFMA(af[m], b0, acc[m][0]); MFMA(af[m], b1, acc[m][1]); }
        __builtin_amdgcn_s_setprio(0);
    }

    // epilogue: C/D layout col = lane&15, row = (lane>>4)*4 + q
    const int r_base = row0 + wr * 128 + (lane >> 4) * 4;
    const int c_base = col0 + wc * 64 + (lane & 15);
#pragma unroll
    for (int n = 0; n < 4; ++n) {
        const int c = c_base + n * 16;
        const float bv = bias[(c & (O_DIM - 1)) * N_BINS + (c >> 8)];
#pragma unroll
        for (int m = 0; m < 8; ++m) {
            const int r = r_base + m * 16;
            float* out = logits + (size_t)r * J_DIM + c;
#pragma unroll
            for (int q = 0; q < 4; ++q)
                out[(size_t)q * J_DIM] = acc[m][n][q] + bv;
        }
    }
}

// ---- fallback GEMM (ws too small): 128x128, on-the-fly bf16 pack -------
__global__ __launch_bounds__(256) void gemm_fb(
    const float* __restrict__ xf,
    const float* __restrict__ Wf,
    const float* __restrict__ bias,
    float* __restrict__ logits)
{
    __shared__ unsigned short Asm_[128 * 32];
    __shared__ unsigned short Bsm_[128 * 32];

    const int tid = threadIdx.x;
    const int bid = blockIdx.x;
    const int swz = (bid & 7) * 1024 + (bid >> 3);
    const int row0 = (swz >> 7) * 128;
    const int col0 = (swz & 127) * 128;

    const int lane = tid & 63;
    const int wid  = tid >> 6;
    const int wr   = wid >> 1;
    const int wc   = wid & 1;

    f32x4 acc[4][4];
#pragma unroll
    for (int m = 0; m < 4; ++m)
#pragma unroll
        for (int n = 0; n < 4; ++n)
            acc[m][n] = (f32x4){0.f, 0.f, 0.f, 0.f};

    const int srow = tid >> 2;
    const int koff = (tid & 3) * 8;
    const int ra0 = row0 + srow, ra1 = row0 + 64 + srow;
    const int rb0 = col0 + srow, rb1 = col0 + 64 + srow;

    unsigned short* la0 = &Asm_[tid * 8];
    unsigned short* la1 = &Asm_[(256 + tid) * 8];
    unsigned short* lb0 = &Bsm_[tid * 8];
    unsigned short* lb1 = &Bsm_[(256 + tid) * 8];

    const float* fa0 = xf + (size_t)ra0 * K_DIM + koff;
    const float* fa1 = xf + (size_t)ra1 * K_DIM + koff;
    const float* fb0 = Wf + (size_t)((rb0 & (O_DIM - 1)) * (N_BINS * K_DIM) + (rb0 >> 8) * K_DIM) + koff;
    const float* fb1 = Wf + (size_t)((rb1 & (O_DIM - 1)) * (N_BINS * K_DIM) + (rb1 >> 8) * K_DIM) + koff;

    const int a_row  = wr * 64 + (lane & 15);
    const int b_row  = wc * 64 + (lane & 15);
    const int k_half = (lane >> 4) * 8;

    for (int kt = 0; kt < K_DIM / 32; ++kt) {
        const int kbase = kt * 32;
        *(u16x8*)la0 = pack8(*(const float4*)(fa0 + kbase), *(const float4*)(fa0 + kbase + 4));
        *(u16x8*)la1 = pack8(*(const float4*)(fa1 + kbase), *(const float4*)(fa1 + kbase + 4));
        *(u16x8*)lb0 = pack8(*(const float4*)(fb0 + kbase), *(const float4*)(fb0 + kbase + 4));
        *(u16x8*)lb1 = pack8(*(const float4*)(fb1 + kbase), *(const float4*)(fb1 + kbase + 4));
        __syncthreads();
        bf16x8 af[4], bg[4];
#pragma unroll
        for (int m = 0; m < 4; ++m) af[m] = *(const bf16x8*)&Asm_[(a_row + m * 16) * 32 + k_half];
#pragma unroll
        for (int n = 0; n < 4; ++n) bg[n] = *(const bf16x8*)&Bsm_[(b_row + n * 16) * 32 + k_half];
#pragma unroll
        for (int m = 0; m < 4; ++m)
#pragma unroll
            for (int n = 0; n < 4; ++n)
                MFMA(af[m], bg[n], acc[m][n]);
        __syncthreads();
    }

    const int r_base = row0 + wr * 64 + (lane >> 4) * 4;
    const int c_base = col0 + wc * 64 + (lane & 15);
#pragma unroll
    for (int n = 0; n < 4; ++n) {
        const int c = c_base + n * 16;
        const float bv = bias[(c & (O_DIM - 1)) * N_BINS + (c >> 8)];
#pragma unroll
        for (int m = 0; m < 4; ++m) {
            const int r = r_base + m * 16;
            float* out = logits + (size_t)r * J_DIM + c;
#pragma unroll
            for (int q = 0; q < 4; ++q)
                out[(size_t)q * J_DIM] = acc[m][n][q] + bv;
        }
    }
}

// ---- gumbel-softmax + grid dot ----------------------------------------
__global__ void softmax_encode_kernel(
    const float* __restrict__ logits,
    const float* __restrict__ gumbel,
    const float* __restrict__ grid,
    float* __restrict__ encoded)
{
    int t = blockIdx.x * 256 + threadIdx.x;
    int g = t >> 4;
    int l = t & 15;
    size_t base = (size_t)g * 64 + l * 4;
    float4 L = *(const float4*)(logits + base);
    float4 G = *(const float4*)(gumbel + base);
    float4 gr = *(const float4*)(grid + l * 4);

    float z0 = (L.x + G.x) * 2.0f;
    float z1 = (L.y + G.y) * 2.0f;
    float z2 = (L.z + G.z) * 2.0f;
    float z3 = (L.w + G.w) * 2.0f;

    float m = fmaxf(fmaxf(z0, z1), fmaxf(z2, z3));
#pragma unroll
    for (int s = 1; s < 16; s <<= 1) m = fmaxf(m, __shfl_xor(m, s, 16));

    float e0 = __expf(z0 - m), e1 = __expf(z1 - m), e2 = __expf(z2 - m), e3 = __expf(z3 - m);
    float ssum = e0 + e1 + e2 + e3;
    float dsum = e0 * gr.x + e1 * gr.y + e2 * gr.z + e3 * gr.w;
#pragma unroll
    for (int s = 1; s < 16; s <<= 1) {
        ssum += __shfl_xor(ssum, s, 16);
        dsum += __shfl_xor(dsum, s, 16);
    }
    if (l == 0) encoded[g] = dsum / ssum;
}

// ---- launch -------------------------------------------------------------
extern "C" void kernel_launch(void* const* d_in, const int* in_sizes, int n_in,
                              void* d_out, int out_size, void* d_ws, size_t ws_size,
                              hipStream_t stream) {
    const float* x      = (const float*)d_in[0];
    const float* W      = (const float*)d_in[1];
    const float* bias   = (const float*)d_in[2];
    const float* grid   = (const float*)d_in[3];
    const float* gumbel = (const float*)d_in[4];

    float* encoded = (float*)d_out;                           // [8192][256]
    float* logits  = (float*)d_out + (size_t)B_ROWS * O_DIM;  // [8192][16384]

    const size_t xb_bytes = (size_t)B_ROWS * K_DIM * 2;   // 32 MiB
    const size_t vb_bytes = (size_t)J_DIM * K_DIM * 2;    // 64 MiB

    if (ws_size >= xb_bytes + vb_bytes) {
        unsigned short* xb = (unsigned short*)d_ws;
        unsigned short* vb = (unsigned short*)((char*)d_ws + xb_bytes);
        cvt_x_kernel<<<(B_ROWS * K_DIM) / 1024, 256, 0, stream>>>(x, xb);
        cvt_w_kernel<<<J_DIM * 2, 256, 0, stream>>>(W, vb);
        gemm8_kernel<<<(B_ROWS / 256) * (J_DIM / 256), 512, 0, stream>>>(xb, vb, bias, logits);
    } else {
        gemm_fb<<<(B_ROWS / 128) * (J_DIM / 128), 256, 0, stream>>>(x, W, bias, logits);
    }

    softmax_encode_kernel<<<(B_ROWS * O_DIM * 16) / 256, 256, 0, stream>>>(logits, gumbel, grid, encoded);
}

// Round 3
// 836.648 us; speedup vs baseline: 1.2208x; 1.0343x over previous
//
#include <hip/hip_runtime.h>
#include <hip/hip_bf16.h>
#include <stdint.h>

typedef __bf16 bf16x8 __attribute__((ext_vector_type(8)));
typedef float f32x4 __attribute__((ext_vector_type(4)));
typedef unsigned short u16x8 __attribute__((ext_vector_type(8)));

#define B_ROWS 8192
#define K_DIM  2048
#define O_DIM  256
#define N_BINS 64
#define J_DIM  (O_DIM * N_BINS)   // 16384
#define NT32   (K_DIM / 32)       // 64 K-tiles of BK=32

__device__ __forceinline__ unsigned short f2bf(float f) {
    union { float f; unsigned u; } v; v.f = f;
    unsigned r = (v.u + 0x7fffu + ((v.u >> 16) & 1u)) >> 16;
    return (unsigned short)r;
}

// ---- conversion kernels ------------------------------------------------
__global__ void cvt_x_kernel(const float* __restrict__ x, unsigned short* __restrict__ xb) {
    int i = (blockIdx.x * 256 + threadIdx.x) * 4;
    float4 v = *(const float4*)(x + i);
    ushort4 o;
    o.x = f2bf(v.x); o.y = f2bf(v.y); o.z = f2bf(v.z); o.w = f2bf(v.w);
    *(ushort4*)(xb + i) = o;
}

// Vb[p][i] = bf16(W[p&255][p>>8][i])  (row permutation fused into the pack)
__global__ void cvt_w_kernel(const float* __restrict__ W, unsigned short* __restrict__ vb) {
    int bid = blockIdx.x;
    int p   = bid >> 1;
    int i0  = (bid & 1) * 1024 + threadIdx.x * 4;
    int src = (p & (O_DIM - 1)) * (N_BINS * K_DIM) + (p >> 8) * K_DIM + i0;
    float4 v = *(const float4*)(W + src);
    ushort4 o;
    o.x = f2bf(v.x); o.y = f2bf(v.y); o.z = f2bf(v.z); o.w = f2bf(v.w);
    *(ushort4*)(vb + (size_t)p * K_DIM + i0) = o;
}

__device__ __forceinline__ u16x8 pack8(float4 a, float4 b) {
    u16x8 r;
    r[0] = f2bf(a.x); r[1] = f2bf(a.y); r[2] = f2bf(a.z); r[3] = f2bf(a.w);
    r[4] = f2bf(b.x); r[5] = f2bf(b.y); r[6] = f2bf(b.z); r[7] = f2bf(b.w);
    return r;
}

// ---- 256x256 quad-buffered BK=32 GEMM ---------------------------------
#define GLDS(gsrc, ldst) \
    __builtin_amdgcn_global_load_lds((const __attribute__((address_space(1))) void*)(gsrc), \
                                     (__attribute__((address_space(3))) void*)(ldst), 16, 0, 0)
#define SBAR()   __builtin_amdgcn_s_barrier()
#define SCHED0() __builtin_amdgcn_sched_barrier(0)
#define WAIT_VM(N)   do { asm volatile("s_waitcnt vmcnt(" #N ")" ::: "memory"); } while (0)
#define WAIT_LGKM(N) do { asm volatile("s_waitcnt lgkmcnt(" #N ")" ::: "memory"); SCHED0(); } while (0)
#define MFMA(a, b, c) (c) = __builtin_amdgcn_mfma_f32_16x16x32_bf16((a), (b), (c), 0, 0, 0)

// One K-tile: ph0 = m0-3 x n0-3 (16 MFMA), ph1 = m4-7 x n0-3 (16 MFMA).
// All 12 ds_reads issued up front; lgkmcnt(4) gates ph0 (a0+bf done, a1 pending).
#define KTILE_BODY(BUF, STAGE_A, STAGE_B) do {                                          \
    bf16x8 a0_[4], a1_[4], bf_[4];                                                      \
    _Pragma("unroll") for (int m_ = 0; m_ < 4; ++m_)                                    \
        a0_[m_] = *(const bf16x8*)&As[BUF][arb + m_ * 16][slot];                        \
    _Pragma("unroll") for (int n_ = 0; n_ < 4; ++n_)                                    \
        bf_[n_] = *(const bf16x8*)&Bs[BUF][brb + n_ * 16][slot];                        \
    _Pragma("unroll") for (int m_ = 0; m_ < 4; ++m_)                                    \
        a1_[m_] = *(const bf16x8*)&As[BUF][arb + 64 + m_ * 16][slot];                   \
    STAGE_A;                                                                            \
    WAIT_LGKM(4);                                                                       \
    __builtin_amdgcn_s_setprio(1);                                                      \
    _Pragma("unroll") for (int m_ = 0; m_ < 4; ++m_) {                                  \
        MFMA(a0_[m_], bf_[0], acc[m_][0]); MFMA(a0_[m_], bf_[1], acc[m_][1]);           \
        MFMA(a0_[m_], bf_[2], acc[m_][2]); MFMA(a0_[m_], bf_[3], acc[m_][3]);           \
    }                                                                                   \
    __builtin_amdgcn_s_setprio(0);                                                      \
    STAGE_B;                                                                            \
    WAIT_LGKM(0);                                                                       \
    __builtin_amdgcn_s_setprio(1);                                                      \
    _Pragma("unroll") for (int m_ = 0; m_ < 4; ++m_) {                                  \
        MFMA(a1_[m_], bf_[0], acc[4 + m_][0]); MFMA(a1_[m_], bf_[1], acc[4 + m_][1]);   \
        MFMA(a1_[m_], bf_[2], acc[4 + m_][2]); MFMA(a1_[m_], bf_[3], acc[4 + m_][3]);   \
    }                                                                                   \
    __builtin_amdgcn_s_setprio(0);                                                      \
} while (0)

__global__ __launch_bounds__(512, 2) void gemm8_kernel(
    const unsigned short* __restrict__ xb,
    const unsigned short* __restrict__ vb,
    const float* __restrict__ bias,
    float* __restrict__ logits)
{
    // 4 buffers x [256 rows][32 K-elems] per operand; 4 x 16 KB x 2 = 128 KB
    __shared__ unsigned short As[4][256][32];
    __shared__ unsigned short Bs[4][256][32];

    const int tid  = threadIdx.x;
    const int lane = tid & 63;
    const int wv   = tid >> 6;
    const int wr   = wv >> 2;      // 0..1 -> A rows wr*128..+127
    const int wc   = wv & 3;       // 0..3 -> B cols wc*64..+63

    const int bid = blockIdx.x;
    // XCD swizzle (2048 blocks, %8==0 -> bijective)
    const int swz  = (bid & 7) * 256 + (bid >> 3);
    const int bm   = (swz >> 8) * 4 + (swz & 3);   // 0..31
    const int bn   = (swz & 255) >> 2;             // 0..63
    const int row0 = bm * 256;
    const int col0 = bn * 256;

    // staging source coords with inverse-swizzle (involution: byte ^= ((byte>>9)&1)<<5)
    const int oss = (tid * 16) ^ (tid & 32);
    const int sr  = oss >> 6;                  // row 0..127 within 8 KB chunk
    const int sc  = (oss >> 1) & 31;           // K-elem 0..31 (multiple of 8)

    const unsigned short* gA = xb + (size_t)(row0 + sr) * K_DIM + sc;
    const unsigned short* gB = vb + (size_t)(col0 + sr) * K_DIM + sc;

    auto stageA = [&](int k, int b) {
        const unsigned short* g = gA + k * 32;
        unsigned short* l = &As[b][0][0] + wv * 512;
        GLDS(g, l);
        GLDS(g + (size_t)128 * K_DIM, l + 4096);
    };
    auto stageB = [&](int k, int b) {
        const unsigned short* g = gB + k * 32;
        unsigned short* l = &Bs[b][0][0] + wv * 512;
        GLDS(g, l);
        GLDS(g + (size_t)128 * K_DIM, l + 4096);
    };

    // fragment read coords; swizzled slot (elem ^16 when lane&8, matching involution)
    const int arb  = wr * 128 + (lane & 15);
    const int brb  = wc * 64 + (lane & 15);
    const int slot = ((lane >> 4) * 8) ^ ((lane & 8) << 1);

    f32x4 acc[8][4];
#pragma unroll
    for (int m = 0; m < 8; ++m)
#pragma unroll
        for (int n = 0; n < 4; ++n)
            acc[m][n] = (f32x4){0.f, 0.f, 0.f, 0.f};

    // prologue: stage K-tiles 0,1,2 (12 GLDS in flight)
    stageA(0, 0); stageB(0, 0);
    stageA(1, 1); stageB(1, 1);
    stageA(2, 2); stageB(2, 2);

    // main loop: kt = 0..59; stage kt+3 (up to 62); one vmcnt+barrier per K-tile
    for (int it = 0; it < 15; ++it) {
        const int kt0 = it * 4;
#pragma unroll
        for (int u = 0; u < 4; ++u) {
            WAIT_VM(8); SBAR();
            KTILE_BODY(u, stageA(kt0 + u + 3, (u + 3) & 3), stageB(kt0 + u + 3, (u + 3) & 3));
        }
    }
    // tail: kt = 60..63 (stage 63 at kt=60; drain 8/8/4/0)
    WAIT_VM(8); SBAR(); KTILE_BODY(0, stageA(63, 3), stageB(63, 3));
    WAIT_VM(8); SBAR(); KTILE_BODY(1, (void)0, (void)0);
    WAIT_VM(4); SBAR(); KTILE_BODY(2, (void)0, (void)0);
    WAIT_VM(0); SBAR(); KTILE_BODY(3, (void)0, (void)0);

    // epilogue: C/D layout col = lane&15, row = (lane>>4)*4 + q
    const int r_base = row0 + wr * 128 + (lane >> 4) * 4;
    const int c_base = col0 + wc * 64 + (lane & 15);
#pragma unroll
    for (int n = 0; n < 4; ++n) {
        const int c = c_base + n * 16;
        const float bv = bias[(c & (O_DIM - 1)) * N_BINS + (c >> 8)];
#pragma unroll
        for (int m = 0; m < 8; ++m) {
            const int r = r_base + m * 16;
            float* out = logits + (size_t)r * J_DIM + c;
#pragma unroll
            for (int q = 0; q < 4; ++q)
                out[(size_t)q * J_DIM] = acc[m][n][q] + bv;
        }
    }
}

// ---- fallback GEMM (ws too small): 128x128, on-the-fly bf16 pack -------
__global__ __launch_bounds__(256) void gemm_fb(
    const float* __restrict__ xf,
    const float* __restrict__ Wf,
    const float* __restrict__ bias,
    float* __restrict__ logits)
{
    __shared__ unsigned short Asm_[128 * 32];
    __shared__ unsigned short Bsm_[128 * 32];

    const int tid = threadIdx.x;
    const int bid = blockIdx.x;
    const int swz = (bid & 7) * 1024 + (bid >> 3);
    const int row0 = (swz >> 7) * 128;
    const int col0 = (swz & 127) * 128;

    const int lane = tid & 63;
    const int wid  = tid >> 6;
    const int wr   = wid >> 1;
    const int wc   = wid & 1;

    f32x4 acc[4][4];
#pragma unroll
    for (int m = 0; m < 4; ++m)
#pragma unroll
        for (int n = 0; n < 4; ++n)
            acc[m][n] = (f32x4){0.f, 0.f, 0.f, 0.f};

    const int srow = tid >> 2;
    const int koff = (tid & 3) * 8;
    const int ra0 = row0 + srow, ra1 = row0 + 64 + srow;
    const int rb0 = col0 + srow, rb1 = col0 + 64 + srow;

    unsigned short* la0 = &Asm_[tid * 8];
    unsigned short* la1 = &Asm_[(256 + tid) * 8];
    unsigned short* lb0 = &Bsm_[tid * 8];
    unsigned short* lb1 = &Bsm_[(256 + tid) * 8];

    const float* fa0 = xf + (size_t)ra0 * K_DIM + koff;
    const float* fa1 = xf + (size_t)ra1 * K_DIM + koff;
    const float* fb0 = Wf + (size_t)((rb0 & (O_DIM - 1)) * (N_BINS * K_DIM) + (rb0 >> 8) * K_DIM) + koff;
    const float* fb1 = Wf + (size_t)((rb1 & (O_DIM - 1)) * (N_BINS * K_DIM) + (rb1 >> 8) * K_DIM) + koff;

    const int a_row  = wr * 64 + (lane & 15);
    const int b_row  = wc * 64 + (lane & 15);
    const int k_half = (lane >> 4) * 8;

    for (int kt = 0; kt < K_DIM / 32; ++kt) {
        const int kbase = kt * 32;
        *(u16x8*)la0 = pack8(*(const float4*)(fa0 + kbase), *(const float4*)(fa0 + kbase + 4));
        *(u16x8*)la1 = pack8(*(const float4*)(fa1 + kbase), *(const float4*)(fa1 + kbase + 4));
        *(u16x8*)lb0 = pack8(*(const float4*)(fb0 + kbase), *(const float4*)(fb0 + kbase + 4));
        *(u16x8*)lb1 = pack8(*(const float4*)(fb1 + kbase), *(const float4*)(fb1 + kbase + 4));
        __syncthreads();
        bf16x8 af[4], bg[4];
#pragma unroll
        for (int m = 0; m < 4; ++m) af[m] = *(const bf16x8*)&Asm_[(a_row + m * 16) * 32 + k_half];
#pragma unroll
        for (int n = 0; n < 4; ++n) bg[n] = *(const bf16x8*)&Bsm_[(b_row + n * 16) * 32 + k_half];
#pragma unroll
        for (int m = 0; m < 4; ++m)
#pragma unroll
            for (int n = 0; n < 4; ++n)
                MFMA(af[m], bg[n], acc[m][n]);
        __syncthreads();
    }

    const int r_base = row0 + wr * 64 + (lane >> 4) * 4;
    const int c_base = col0 + wc * 64 + (lane & 15);
#pragma unroll
    for (int n = 0; n < 4; ++n) {
        const int c = c_base + n * 16;
        const float bv = bias[(c & (O_DIM - 1)) * N_BINS + (c >> 8)];
#pragma unroll
        for (int m = 0; m < 4; ++m) {
            const int r = r_base + m * 16;
            float* out = logits + (size_t)r * J_DIM + c;
#pragma unroll
            for (int q = 0; q < 4; ++q)
                out[(size_t)q * J_DIM] = acc[m][n][q] + bv;
        }
    }
}

// ---- gumbel-softmax + grid dot ----------------------------------------
__global__ void softmax_encode_kernel(
    const float* __restrict__ logits,
    const float* __restrict__ gumbel,
    const float* __restrict__ grid,
    float* __restrict__ encoded)
{
    int t = blockIdx.x * 256 + threadIdx.x;
    int g = t >> 4;
    int l = t & 15;
    size_t base = (size_t)g * 64 + l * 4;
    float4 L = *(const float4*)(logits + base);
    float4 G = *(const float4*)(gumbel + base);
    float4 gr = *(const float4*)(grid + l * 4);

    float z0 = (L.x + G.x) * 2.0f;
    float z1 = (L.y + G.y) * 2.0f;
    float z2 = (L.z + G.z) * 2.0f;
    float z3 = (L.w + G.w) * 2.0f;

    float m = fmaxf(fmaxf(z0, z1), fmaxf(z2, z3));
#pragma unroll
    for (int s = 1; s < 16; s <<= 1) m = fmaxf(m, __shfl_xor(m, s, 16));

    float e0 = __expf(z0 - m), e1 = __expf(z1 - m), e2 = __expf(z2 - m), e3 = __expf(z3 - m);
    float ssum = e0 + e1 + e2 + e3;
    float dsum = e0 * gr.x + e1 * gr.y + e2 * gr.z + e3 * gr.w;
#pragma unroll
    for (int s = 1; s < 16; s <<= 1) {
        ssum += __shfl_xor(ssum, s, 16);
        dsum += __shfl_xor(dsum, s, 16);
    }
    if (l == 0) encoded[g] = dsum / ssum;
}

// ---- launch -------------------------------------------------------------
extern "C" void kernel_launch(void* const* d_in, const int* in_sizes, int n_in,
                              void* d_out, int out_size, void* d_ws, size_t ws_size,
                              hipStream_t stream) {
    const float* x      = (const float*)d_in[0];
    const float* W      = (const float*)d_in[1];
    const float* bias   = (const float*)d_in[2];
    const float* grid   = (const float*)d_in[3];
    const float* gumbel = (const float*)d_in[4];

    float* encoded = (float*)d_out;                           // [8192][256]
    float* logits  = (float*)d_out + (size_t)B_ROWS * O_DIM;  // [8192][16384]

    const size_t xb_bytes = (size_t)B_ROWS * K_DIM * 2;   // 32 MiB
    const size_t vb_bytes = (size_t)J_DIM * K_DIM * 2;    // 64 MiB

    if (ws_size >= xb_bytes + vb_bytes) {
        unsigned short* xb = (unsigned short*)d_ws;
        unsigned short* vb = (unsigned short*)((char*)d_ws + xb_bytes);
        cvt_x_kernel<<<(B_ROWS * K_DIM) / 1024, 256, 0, stream>>>(x, xb);
        cvt_w_kernel<<<J_DIM * 2, 256, 0, stream>>>(W, vb);
        gemm8_kernel<<<(B_ROWS / 256) * (J_DIM / 256), 512, 0, stream>>>(xb, vb, bias, logits);
    } else {
        gemm_fb<<<(B_ROWS / 128) * (J_DIM / 128), 256, 0, stream>>>(x, W, bias, logits);
    }

    softmax_encode_kernel<<<(B_ROWS * O_DIM * 16) / 256, 256, 0, stream>>>(logits, gumbel, grid, encoded);
}